// Round 10
// baseline (2428.699 us; speedup 1.0000x reference)
//
#include <hip/hip_runtime.h>

// ---------------------------------------------------------------------------
// XiRNN (peephole LSTM) on MI355X.  B=64, T=188, I=512, H=R=1024.
//   k_prep : fp32->bf16 for x, W_ih; h0/c0 split hi+lo, BOTH slots written,
//            every ushort tagged gen=3 (2-bit in-band generation, bits[1:0]).
//   k_px   : px GEMM with 4x A-reuse (R16).
//   k_scan : persistent, 256 blocks (1/CU). R17 sync = flag-paced + tag-valid:
//            producer posts flag RIGHT AFTER issuing state stores (NO vmcnt
//            drain); consumer polls flag (pacing, R11 wave0+go_word), gathers,
//            then validates per-ushort 2-bit generation tags, retrying only
//            the (rare) in-flight window. Removes the drain RT: chain 3RT->2RT.
//   Protocol history: R9 batched gather 1156 / R10 poll-flood FAIL / R11
//   go_word 1140 / R12 balance neutral / R13-14 tag-sync accuracy FAIL
//   (prep-slot + 1-bit gen aliasing) / R15 tags CORRECT (0.0039) but unpaced
//   retries flooded fabric (1750) / R16 non-scan trim (total 1446).
//   R17 reuses R15's PROVEN tag machinery (gen=((t-1)>>1)&3, prep=3, both
//   slots, exact absorption via hi/lo splits incl. h) + R11's proven pacing.
//   Overwrite closure with issue-semantics flags: producer at t+1 polled
//   flags>=t+1 => every consumer finished (validated) its step-t gather =>
//   its t-1 data is in registers before the slot is overwritten.
// ---------------------------------------------------------------------------

#define T_N 188

// ws byte offsets (256-aligned). hstlo reuses the old wcomb region.
#define WS_PX     0UL           // ushort[188*4096*64]   = 98,566,144 B
#define WS_XB     98566144UL    // ushort[64*188*512]    = 12,320,768 B
#define WS_WIHB   110886912UL   // ushort[4096*512]      =  4,194,304 B
#define WS_HSTLO  115081216UL   // ushort[2][64][1024]   =    262,144 B  (h_lo)
#define WS_HST    127664128UL   // ushort[2][64][1024]   =    262,144 B  (h_hi)
#define WS_CST    127926272UL   // ushort[2][64][1024]   =    262,144 B  (c_hi)
#define WS_FLAGS  128188416UL   // int[1024]
#define WS_CSTLO  132386816UL   // ushort[2][64][1024]   =    262,144 B  (c_lo)

typedef __attribute__((ext_vector_type(8))) short short8;
typedef __attribute__((ext_vector_type(4))) float f4;

__device__ __forceinline__ float b2f(unsigned short u) {
    union { unsigned int i; float f; } v; v.i = ((unsigned int)u) << 16; return v.f;
}
__device__ __forceinline__ unsigned short f2b(float f) {
    unsigned int u = __float_as_uint(f);
    return (unsigned short)((u + 0x7FFFu + ((u >> 16) & 1u)) >> 16);
}
__device__ __forceinline__ float sigf(float x) { return 1.0f / (1.0f + __expf(-x)); }
__device__ __forceinline__ float tanh_(float x) {
    float e = __expf(2.0f * x); return 1.0f - 2.0f / (e + 1.0f);
}
#define MFMA(a, b, c) __builtin_amdgcn_mfma_f32_16x16x32_bf16((a), (b), (c), 0, 0, 0)

// 16B device-coherent load (bypass L1/L2). Result NOT tracked by compiler
// waitcnt logic — caller must s_waitcnt vmcnt(0) + sched_barrier(0) before use.
#define LD16(dst, addr) \
    asm volatile("global_load_dwordx4 %0, %1, off sc0 sc1" : "=&v"(dst) : "v"(addr))

// OR-reduce XOR of a chunk's 4 dwords vs tag pattern; bits 0x00030003 set
// => some ushort's 2-bit generation != expected.
__device__ __forceinline__ unsigned int tagxor(short8 v, unsigned int pat) {
    union { short8 s; unsigned int d[4]; } u; u.s = v;
    return (u.d[0] ^ pat) | (u.d[1] ^ pat) | (u.d[2] ^ pat) | (u.d[3] ^ pat);
}

// 16-FMA ballast burst (keeps SIMD active while waiting; R11-proven).
#define BALLAST(bal)                                                       \
    _Pragma("unroll")                                                      \
    for (int u_ = 0; u_ < 16; ++u_) bal = __builtin_fmaf(bal, 1.0000001f, 1e-7f)

__device__ __forceinline__ f4 px_init(const unsigned short* px, int t, int gate, int jg, int brow) {
    unsigned long long pv =
        *(const unsigned long long*)(px + ((long)(t * 4 + gate) * 1024 + jg) * 64 + brow);
    f4 r;
    r[0] = b2f((unsigned short)pv);
    r[1] = b2f((unsigned short)(pv >> 16));
    r[2] = b2f((unsigned short)(pv >> 32));
    r[3] = b2f((unsigned short)(pv >> 48));
    return r;
}

// ---------------------------------------------------------------------------
// k_prep: x->xb, wih->wihb; h0/c0 -> hi+lo state, BOTH slots, gen-3 tags
// (bits[1:0] of every ushort). lo computed from TAGGED hi => exact absorption.
__global__ void k_prep(const float* __restrict__ x, const float* __restrict__ h0,
                       const float* __restrict__ c0, const float* __restrict__ wih,
                       unsigned short* __restrict__ xb, unsigned short* __restrict__ wihb,
                       unsigned short* __restrict__ hst, unsigned short* __restrict__ hstlo,
                       unsigned short* __restrict__ cst, unsigned short* __restrict__ cstlo,
                       int* __restrict__ flags) {
    const long NX4 = 1540096, NWIH4 = 524288, NH4 = 16384;
    const long total = NX4 + NWIH4 + NH4 + NH4;
    long gtid = (long)blockIdx.x * blockDim.x + threadIdx.x;
    for (long i = gtid; i < total; i += (long)gridDim.x * blockDim.x) {
        const float* src; unsigned short* dst; unsigned short* lo_dst = nullptr; long off = i;
        bool tag_state = false;
        if (off < NX4)                  { src = x;   dst = xb; }
        else if ((off -= NX4) < NWIH4)  { src = wih; dst = wihb; }
        else if ((off -= NWIH4) < NH4)  { src = h0;  dst = hst; lo_dst = hstlo; tag_state = true; }
        else { off -= NH4;                src = c0;  dst = cst; lo_dst = cstlo; tag_state = true; }
        float4 v = ((const float4*)src)[off];
        unsigned short hx = f2b(v.x), hy = f2b(v.y), hz = f2b(v.z), hw = f2b(v.w);
        if (tag_state) { hx |= 3u; hy |= 3u; hz |= 3u; hw |= 3u; }
        unsigned long long o = (unsigned long long)hx
            | ((unsigned long long)hy << 16)
            | ((unsigned long long)hz << 32)
            | ((unsigned long long)hw << 48);
        *(unsigned long long*)(dst + off * 4) = o;
        if (tag_state) *(unsigned long long*)(dst + 65536 + off * 4) = o;    // both slots
        if (lo_dst) {
            unsigned short lx = (unsigned short)(f2b(v.x - b2f(hx)) | 3u);
            unsigned short ly = (unsigned short)(f2b(v.y - b2f(hy)) | 3u);
            unsigned short lz = (unsigned short)(f2b(v.z - b2f(hz)) | 3u);
            unsigned short lw = (unsigned short)(f2b(v.w - b2f(hw)) | 3u);
            unsigned long long l = (unsigned long long)lx
                | ((unsigned long long)ly << 16)
                | ((unsigned long long)lz << 32)
                | ((unsigned long long)lw << 48);
            *(unsigned long long*)(lo_dst + off * 4) = l;
            *(unsigned long long*)(lo_dst + 65536 + off * 4) = l;
        }
    }
    if (gtid < 1024) flags[gtid] = 0;
}

// ---------------------------------------------------------------------------
// k_px (R16): block = (t, 256-col slab); wave owns a 64-col slab x M=64.
__global__ void __launch_bounds__(256) k_px(const unsigned short* __restrict__ xb,
                                            const unsigned short* __restrict__ wihb,
                                            const float* __restrict__ bias,
                                            unsigned short* __restrict__ px) {
    const int t = blockIdx.y;
    const int wv = threadIdx.x >> 6, lane = threadIdx.x & 63;
    const int col = lane & 15, quad = lane >> 4;
    const int nb = blockIdx.x * 256 + wv * 64;
    f4 acc[4][4];
#pragma unroll
    for (int nt = 0; nt < 4; ++nt) {
        const float bn = bias[nb + nt * 16 + col];
#pragma unroll
        for (int mt = 0; mt < 4; ++mt) {
            acc[mt][nt][0] = bn; acc[mt][nt][1] = bn; acc[mt][nt][2] = bn; acc[mt][nt][3] = bn;
        }
    }
#pragma unroll 4
    for (int kk = 0; kk < 16; ++kk) {
        short8 bf[4], af[4];
#pragma unroll
        for (int nt = 0; nt < 4; ++nt)
            bf[nt] = *(const short8*)(wihb + (nb + nt * 16 + col) * 512 + kk * 32 + quad * 8);
#pragma unroll
        for (int mt = 0; mt < 4; ++mt)
            af[mt] = *(const short8*)(xb + ((mt * 16 + col) * 188 + t) * 512 + kk * 32 + quad * 8);
#pragma unroll
        for (int mt = 0; mt < 4; ++mt)
#pragma unroll
            for (int nt = 0; nt < 4; ++nt)
                acc[mt][nt] = MFMA(af[mt], bf[nt], acc[mt][nt]);
    }
#pragma unroll
    for (int nt = 0; nt < 4; ++nt) {
        const int n = nb + nt * 16 + col;
        const long pb = ((long)(t * 4 + (n >> 10)) * 1024 + (n & 1023)) * 64;
#pragma unroll
        for (int mt = 0; mt < 4; ++mt) {
            unsigned long long o = (unsigned long long)f2b(acc[mt][nt][0])
                | ((unsigned long long)f2b(acc[mt][nt][1]) << 16)
                | ((unsigned long long)f2b(acc[mt][nt][2]) << 32)
                | ((unsigned long long)f2b(acc[mt][nt][3]) << 48);
            *(unsigned long long*)(px + pb + mt * 16 + quad * 4) = o;
        }
    }
}

// ---------------------------------------------------------------------------
// Persistent scan. cu: group g = cu>>6 (16 batch rows), cig = cu&63 (16 cols).
// 4 waves: kh = wv>>1 (K-half), ts = wv&1.
//   ts0: gates {i,f,g,o} = px + h_hi@W_hh + h_lo@W_hh   (128 MFMA)
//   ts1: peephole {ri,rf} = c_hi@W_hi + c_hi@W_lo + c_lo@W_hi (96 MFMA)
// In-kernel weight convert (R16). Sync: flag-paced gather + 2-bit tag valid.
__global__ void __launch_bounds__(256, 1) k_scan(
    const float* __restrict__ whh, const float* __restrict__ wrec,
    const float* __restrict__ c0, const int* __restrict__ lengths,
    const unsigned short* __restrict__ px, unsigned short* __restrict__ hst,
    unsigned short* __restrict__ hstlo, unsigned short* __restrict__ cst,
    unsigned short* __restrict__ cstlo, int* __restrict__ flags,
    float* __restrict__ out) {
    const int cu = blockIdx.x;
    const int g = cu >> 6, cig = cu & 63;
    const int jbase = cig * 16, b0 = g * 16;
    const int tid = threadIdx.x, wv = tid >> 6, lane = tid & 63;
    const int kh = wv >> 1, ts = wv & 1;
    const int kbase = kh * 512;
    const int col = lane & 15, quad = lane >> 4;

    __shared__ float pre[2][2][6][16][16];   // [slot][kh][tile][b][j]  24 KB
    __shared__ float c_loc[16][16];          // fp32 local c (never rounded)
    __shared__ int go_word;                  // LDS release hand-off

    // One-time: weights fp32 -> bf16 regs (in-register convert, R16).
    short8 wf[4][16];
    if (ts == 0) {
#pragma unroll
        for (int tile = 0; tile < 4; ++tile) {
            const float* src = whh + (long)(tile * 1024 + jbase + col) * 1024 + kbase + quad * 8;
#pragma unroll
            for (int kk = 0; kk < 16; ++kk) {
                float4 a = *(const float4*)(src + kk * 32);
                float4 b = *(const float4*)(src + kk * 32 + 4);
                union { unsigned short u[8]; short8 s; } P;
                P.u[0] = f2b(a.x); P.u[1] = f2b(a.y); P.u[2] = f2b(a.z); P.u[3] = f2b(a.w);
                P.u[4] = f2b(b.x); P.u[5] = f2b(b.y); P.u[6] = f2b(b.z); P.u[7] = f2b(b.w);
                wf[tile][kk] = P.s;
            }
        }
    } else {
#pragma unroll
        for (int tl = 0; tl < 2; ++tl) {
            const float* src = wrec + (long)(tl * 1024 + jbase + col) * 1024 + kbase + quad * 8;
#pragma unroll
            for (int kk = 0; kk < 16; ++kk) {
                float4 a = *(const float4*)(src + kk * 32);
                float4 b = *(const float4*)(src + kk * 32 + 4);
                float w[8] = {a.x, a.y, a.z, a.w, b.x, b.y, b.z, b.w};
                union { unsigned short u[8]; short8 s; } H, L;
#pragma unroll
                for (int e = 0; e < 8; ++e) {
                    unsigned short hi = f2b(w[e]);
                    H.u[e] = hi;
                    L.u[e] = f2b(w[e] - b2f(hi));
                }
                wf[tl][kk] = H.s;
                wf[2 + tl][kk] = L.s;
            }
        }
    }
    {
        int b = tid >> 4, j = tid & 15;
        c_loc[b][j] = c0[(b0 + b) * 1024 + jbase + j];
    }
    if (tid == 0) go_word = 0;
    const int my_len = lengths[b0 + (tid >> 4)];
    float bal = (float)lane + 1.0f;
    __syncthreads();

    float* out_h = out;
    float* out_c = out + 12320768;

    for (int t = 0; t < T_N; ++t) {
        const int sl_r = (t + 1) & 1, sl_w = t & 1, ps = t & 1;
        // R15-proven gen schedule: data written at step t carries (t>>1)&3;
        // prep ("t=-1") carries 3. Expected at step t:
        const int genr = (t == 0) ? 3 : (((t - 1) >> 1) & 3);
        const unsigned int pat = (unsigned int)genr * 0x00010001u;
        const unsigned int gw = (unsigned int)((t >> 1) & 3);

        // px loads (ts0/kh0 only) are state-independent: in flight during poll.
        f4 pxv[4];
        if (ts == 0 && kh == 0) {
#pragma unroll
            for (int tile = 0; tile < 4; ++tile)
                pxv[tile] = px_init(px, t, tile, jbase + col, b0 + quad * 4);
        }

        if (t > 0) {
            if (wv == 0) {
                const int* fp = flags + g * 64 + lane;
                for (;;) {
                    int a = __hip_atomic_load(fp, __ATOMIC_RELAXED, __HIP_MEMORY_SCOPE_AGENT);
                    if (__all(a >= t)) break;
                    BALLAST(bal);
                }
                if (lane == 0)
                    __hip_atomic_store(&go_word, t, __ATOMIC_RELAXED, __HIP_MEMORY_SCOPE_WORKGROUP);
            } else {
                for (;;) {
                    int gwd = __hip_atomic_load(&go_word, __ATOMIC_RELAXED, __HIP_MEMORY_SCOPE_WORKGROUP);
                    if (gwd >= t) break;
                    BALLAST(bal);
                }
            }
            asm volatile("" ::: "memory");
        }

        const int sbase = sl_r * 65536 + (b0 + col) * 1024 + kbase + quad * 8;

        if (ts == 0) {
            // Validated gather: h_hi + h_lo (32 x 16B); flag already paced us,
            // so retries are rare (stores were issued before the flag).
            short8 hbuf[16], hlb[16];
            f4 acc[4];
#pragma unroll
            for (int tile = 0; tile < 4; ++tile) {
                if (kh == 0) acc[tile] = pxv[tile];
                else { acc[tile][0] = 0.f; acc[tile][1] = 0.f; acc[tile][2] = 0.f; acc[tile][3] = 0.f; }
            }
            for (;;) {
#pragma unroll
                for (int kk = 0; kk < 16; ++kk) LD16(hbuf[kk], hst + sbase + kk * 32);
#pragma unroll
                for (int kk = 0; kk < 16; ++kk) LD16(hlb[kk], hstlo + sbase + kk * 32);
                asm volatile("s_waitcnt vmcnt(0)" ::: "memory");
                __builtin_amdgcn_sched_barrier(0);
                unsigned int bad = 0;
#pragma unroll
                for (int kk = 0; kk < 16; ++kk)
                    bad |= tagxor(hbuf[kk], pat) | tagxor(hlb[kk], pat);
                if (__all((bad & 0x00030003u) == 0u)) break;
                BALLAST(bal);
            }
#pragma unroll
            for (int kk = 0; kk < 16; ++kk) {
                acc[0] = MFMA(hbuf[kk], wf[0][kk], acc[0]);
                acc[1] = MFMA(hbuf[kk], wf[1][kk], acc[1]);
                acc[2] = MFMA(hbuf[kk], wf[2][kk], acc[2]);
                acc[3] = MFMA(hbuf[kk], wf[3][kk], acc[3]);
            }
#pragma unroll
            for (int kk = 0; kk < 16; ++kk) {     // h_lo compensation pass
                acc[0] = MFMA(hlb[kk], wf[0][kk], acc[0]);
                acc[1] = MFMA(hlb[kk], wf[1][kk], acc[1]);
                acc[2] = MFMA(hlb[kk], wf[2][kk], acc[2]);
                acc[3] = MFMA(hlb[kk], wf[3][kk], acc[3]);
            }
#pragma unroll
            for (int tile = 0; tile < 4; ++tile)
#pragma unroll
                for (int r = 0; r < 4; ++r) pre[ps][kh][tile][quad * 4 + r][col] = acc[tile][r];
        } else {
            short8 chb[16], clb[16];
            for (;;) {
#pragma unroll
                for (int kk = 0; kk < 16; ++kk) LD16(chb[kk], cst + sbase + kk * 32);
#pragma unroll
                for (int kk = 0; kk < 16; ++kk) LD16(clb[kk], cstlo + sbase + kk * 32);
                asm volatile("s_waitcnt vmcnt(0)" ::: "memory");
                __builtin_amdgcn_sched_barrier(0);
                unsigned int bad = 0;
#pragma unroll
                for (int kk = 0; kk < 16; ++kk)
                    bad |= tagxor(chb[kk], pat) | tagxor(clb[kk], pat);
                if (__all((bad & 0x00030003u) == 0u)) break;
                BALLAST(bal);
            }
            f4 a0 = {0.f, 0.f, 0.f, 0.f}, a1 = a0, a2 = a0, a3 = a0, a4 = a0, a5 = a0;
#pragma unroll
            for (int kk = 0; kk < 16; ++kk) {
                a0 = MFMA(chb[kk], wf[0][kk], a0);   // c_hi @ ri_hi
                a1 = MFMA(chb[kk], wf[1][kk], a1);   // c_hi @ rf_hi
                a2 = MFMA(chb[kk], wf[2][kk], a2);   // c_hi @ ri_lo
                a3 = MFMA(chb[kk], wf[3][kk], a3);   // c_hi @ rf_lo
                a4 = MFMA(clb[kk], wf[0][kk], a4);   // c_lo @ ri_hi
                a5 = MFMA(clb[kk], wf[1][kk], a5);   // c_lo @ rf_hi
            }
#pragma unroll
            for (int r = 0; r < 4; ++r) {
                pre[ps][kh][4][quad * 4 + r][col] = a0[r] + a2[r] + a4[r];
                pre[ps][kh][5][quad * 4 + r][col] = a1[r] + a3[r] + a5[r];
            }
        }
        __syncthreads();   // bar1: pre[] complete

        float hn, cn; long ob;
        {
            const int b = tid >> 4, j = tid & 15;
            float pi = pre[ps][0][0][b][j] + pre[ps][1][0][b][j] + pre[ps][0][4][b][j] + pre[ps][1][4][b][j];
            float pf = pre[ps][0][1][b][j] + pre[ps][1][1][b][j] + pre[ps][0][5][b][j] + pre[ps][1][5][b][j];
            float pg = pre[ps][0][2][b][j] + pre[ps][1][2][b][j];
            float po = pre[ps][0][3][b][j] + pre[ps][1][3][b][j];
            const float cprev = c_loc[b][j];
            const float iv = sigf(pi), fv = sigf(pf), gv = tanh_(pg);
            cn = fv * cprev + iv * gv;
            float ov = sigf(po + cn);
            hn = ov * tanh_(cn);
            if (t >= my_len) { hn = 0.f; cn = 0.f; }
            c_loc[b][j] = cn;
            ob = (long)(b0 + b) * 192512 + (long)t * 1024 + jbase + j;
            const int sidx = sl_w * 65536 + (b0 + b) * 1024 + jbase + j;
            // Tag every ushort with the 2-bit gen; lo computed from TAGGED hi
            // (exact absorption); lo's own tag ~2^-15 absolute.
            unsigned short hhw = (unsigned short)((f2b(hn) & 0xFFFCu) | gw);
            unsigned short hlw = (unsigned short)((f2b(hn - b2f(hhw)) & 0xFFFCu) | gw);
            unsigned short chw = (unsigned short)((f2b(cn) & 0xFFFCu) | gw);
            unsigned short clw = (unsigned short)((f2b(cn - b2f(chw)) & 0xFFFCu) | gw);
            __hip_atomic_store(&hst[sidx],   hhw, __ATOMIC_RELAXED, __HIP_MEMORY_SCOPE_AGENT);
            __hip_atomic_store(&hstlo[sidx], hlw, __ATOMIC_RELAXED, __HIP_MEMORY_SCOPE_AGENT);
            __hip_atomic_store(&cst[sidx],   chw, __ATOMIC_RELAXED, __HIP_MEMORY_SCOPE_AGENT);
            __hip_atomic_store(&cstlo[sidx], clw, __ATOMIC_RELAXED, __HIP_MEMORY_SCOPE_AGENT);
        }
        // R17 release: NO vmcnt drain. Barrier = all waves ISSUED their state
        // stores; flag follows. Consumers validate tags; stores and flag ride
        // the same fabric, so by the time a paced gather arrives, data is in.
        __syncthreads();
        if (tid == 0)
            __hip_atomic_store(&flags[cu], t + 1, __ATOMIC_RELAXED, __HIP_MEMORY_SCOPE_AGENT);
        // Out stores after the flag: off the critical path (drained by the
        // next step's gather vmcnt(0), whose wait overlaps the poll anyway).
        out_h[ob] = hn;
        out_c[ob] = cn;
    }
    asm volatile("" :: "v"(bal));   // keep ballast live
}

// ---------------------------------------------------------------------------
extern "C" void kernel_launch(void* const* d_in, const int* in_sizes, int n_in,
                              void* d_out, int out_size, void* d_ws, size_t ws_size,
                              hipStream_t stream) {
    const float* x    = (const float*)d_in[0];
    const float* h0   = (const float*)d_in[1];
    const float* c0   = (const float*)d_in[2];
    const float* wih  = (const float*)d_in[3];
    const float* whh  = (const float*)d_in[4];
    const float* wrec = (const float*)d_in[5];
    const float* bias = (const float*)d_in[6];
    const int* lengths = (const int*)d_in[7];

    char* ws = (char*)d_ws;
    unsigned short* px     = (unsigned short*)(ws + WS_PX);
    unsigned short* xb     = (unsigned short*)(ws + WS_XB);
    unsigned short* wihb   = (unsigned short*)(ws + WS_WIHB);
    unsigned short* hst    = (unsigned short*)(ws + WS_HST);
    unsigned short* hstlo  = (unsigned short*)(ws + WS_HSTLO);
    unsigned short* cst    = (unsigned short*)(ws + WS_CST);
    unsigned short* cstlo  = (unsigned short*)(ws + WS_CSTLO);
    int* flags             = (int*)(ws + WS_FLAGS);
    float* out = (float*)d_out;

    hipLaunchKernelGGL(k_prep, dim3(2048), dim3(256), 0, stream,
                       x, h0, c0, wih, xb, wihb, hst, hstlo, cst, cstlo, flags);
    hipLaunchKernelGGL(k_px, dim3(16, 188), dim3(256), 0, stream, xb, wihb, bias, px);
    hipLaunchKernelGGL(k_scan, dim3(256), dim3(256), 0, stream,
                       whh, wrec, c0, lengths, px, hst, hstlo, cst, cstlo, flags, out);
}